// Round 9
// baseline (1284.482 us; speedup 1.0000x reference)
//
#include <hip/hip_runtime.h>
#include <math.h>
#include <stdint.h>

// ---------------------------------------------------------------------------
// Muskingum-Cunge tree routing, spatially-pipelined persistent kernel, v9.
//
// v8 post-mortem (with v3/v5): period tracks TRANSCENDENTAL COUNT, not chain
// depth (v8/v5 period ratio 1.20 == trans ratio 19/16; chain-shortening
// regressed). Wave64 trans ops occupy the quarter-width trans pipe ~32+ cy
// each and waves issue in order -> trans ops serialize even when dataflow-
// parallel. v9 = v5's exact math with both exp2 per substep replaced by a
// SOFTWARE exp2 (rint reduction, deg-6 Taylor on |f|<=0.5, rel err 1.2e-7,
// globally valid - no trust region; integer exponent insert, args proven in
// [-14,21]). Trans/step: 16 -> 8 (4 log2 + 4 rcp, de-clustered by the VALU
// poly work between them). VALU is 2cy/op and compiler-schedulable into
// chain bubbles.
//
// Protocol unchanged from v5: per-level persistent blocks, batched (8-step)
// ring handoff, tagged 8-byte relaxed agent-scope atomics (sc0 sc1, MALL-
// coherent, no bulk cache maintenance), next-batch register prefetch,
// per-wave progress counters, no barriers/fences in the steady path.
// ---------------------------------------------------------------------------

#define N_LEVELS   14
#define T_STEPS    2048
#define NR_TOTAL   16383
#define DT_SUB_F   21600.0f
#define EPS_F      1e-6f
#define NBLOCKS    71
#define CTR_STRIDE 8             // ints per wave counter (32 B apart)
#define RING_BYTE_OFF 16384
#define BATCH      8
#define NBATCH     (T_STEPS / BATCH)

__device__ __constant__ int kSize[N_LEVELS] = {8192,4096,2048,1024,512,256,128,64,32,16,8,4,2,1};
__device__ __constant__ int kEpb [N_LEVELS] = {256,256,256,256,256,256,128,64,32,16,8,4,2,1};
__device__ __constant__ int kBlkStart[N_LEVELS+1] = {0,32,48,56,60,62,63,64,65,66,67,68,69,70,71};
__device__ __constant__ int kOffL[N_LEVELS] = {0,8192,12288,14336,15360,15872,16128,16256,16320,16352,16368,16376,16380,16382};
// pair-sum entries before level l
__device__ __constant__ int kOffH[N_LEVELS-1] = {0,4096,6144,7168,7680,7936,8064,8128,8160,8176,8184,8188,8190};

#if __has_builtin(__builtin_amdgcn_logf)
#define FAST_LOG2(x) __builtin_amdgcn_logf(x)
#else
#define FAST_LOG2(x) log2f(x)
#endif
#if __has_builtin(__builtin_amdgcn_rcpf)
#define FAST_RCP(x) __builtin_amdgcn_rcpf(x)
#else
#define FAST_RCP(x) (1.0f/(x))
#endif

// software exp2: VALU-only (no trans pipe). Valid for |y| < 60 (our args are
// in [-14,21] by construction). rel err ~1.2e-7 (deg-6 Taylor, |f|<=0.5).
__device__ __forceinline__ float sw_exp2(float y) {
    float n  = rintf(y);                     // v_rndne_f32
    float f  = y - n;                        // |f| <= 0.5
    float f2 = f * f;
    float pA = fmaf(f, 0.69314718056f, 1.0f);
    float pB = fmaf(f, 0.05550410866f, 0.24022650696f);
    float pC = fmaf(f, 0.00133335581f, 0.00961812911f);
    float pD = fmaf(f2, 0.00015403530f, pC);
    float f4 = f2 * f2;
    float p  = fmaf(f4, pD, fmaf(f2, pB, pA));
    int   ni = (int)n;                       // n integral -> exact
    float s  = __int_as_float((ni + 127) << 23);   // 2^n
    return p * s;
}

#define ATOMIC_LD_RLX(p)   __hip_atomic_load((p), __ATOMIC_RELAXED, __HIP_MEMORY_SCOPE_AGENT)
#define ATOMIC_ST_RLX(p,v) __hip_atomic_store((p), (v), __ATOMIC_RELAXED, __HIP_MEMORY_SCOPE_AGENT)

__global__ __launch_bounds__(256)
void mc_route_pipe9(const float* __restrict__ lat,
                    const float* __restrict__ logn,
                    const float* __restrict__ len,
                    const float* __restrict__ slope,
                    const float* __restrict__ wcoef,
                    const float* __restrict__ wexp,
                    const float* __restrict__ dcoef,
                    const float* __restrict__ dexp,
                    float* __restrict__ out,
                    int* __restrict__ prog,
                    unsigned long long* __restrict__ ring,
                    int slotsB)
{
    const int bid = blockIdx.x;
    const int tid = threadIdx.x;

    int lvl = 0;
#pragma unroll
    for (int l = 1; l < N_LEVELS; ++l)
        if (bid >= kBlkStart[l]) lvl = l;

    const int  bl     = bid - kBlkStart[lvl];
    const int  epb    = kEpb[lvl];
    const int  size   = kSize[lvl];
    const bool validT = (tid < epb);
    const int  e      = bl * epb + (validT ? tid : (epb - 1));
    const int  rr     = kOffL[lvl] + e;

    // -------- per-reach constants (chain-fused form, v5-verified) ----------
    // K2 = 2*dx/c            = exp2( eK*lq + cK2 )
    // tX = Qref/(2*c*w*S*dx) = exp2( et*lq + ct )
    const float dx      = len[rr];
    const float S       = slope[rr];
    const float sqrtS_n = sqrtf(S) * expf(-logn[rr]);        // sqrt(S)/n
    const float de23    = 0.66666667f * dexp[rr];
    const float l2dc    = log2f(dcoef[rr]);
    const float l2base  = log2f(0.6f / sqrtS_n) - 0.66666667f * l2dc;
    const float eK      = -de23;
    const float cK2     = log2f(2.0f * dx) + l2base;
    const float et      = 1.0f - de23 - wexp[rr];
    const float ct      = log2f(0.5f / (S * dx)) + l2base - log2f(wcoef[rr]);

    // -------- pipeline wiring ----------------------------------------------
    const bool hasProd = (lvl > 0);
    const bool hasCons = (lvl < N_LEVELS - 1);
    const int  SB8     = slotsB * BATCH;
    const int  sBm1    = slotsB - 1;
    const unsigned long long* ringUp = hasProd ? ring + (size_t)kOffH[lvl-1] * SB8 : ring;
    unsigned long long*       ringMy = hasCons ? ring + (size_t)kOffH[lvl]   * SB8 : ring;
    const int halfSize = size >> 1;
    const int upSlotSz = size * BATCH;
    const int mySlotSz = halfSize * BATCH;

    int c0i = 0, c1i = 0;
    if (hasCons) {
        const int ceLo = (bl * epb) >> 1;
        const int ceHi = ((bl + 1) * epb - 1) >> 1;
        const int epbN = kEpb[lvl+1];
        const int cb   = kBlkStart[lvl+1] + ceLo / epbN;
        const int le0  = ceLo - (ceLo / epbN) * epbN;
        const int le1  = ceHi - (ceHi / epbN) * epbN;
        c0i = (cb * 4 + (le0 >> 6)) * CTR_STRIDE;
        c1i = (cb * 4 + (le1 >> 6)) * CTR_STRIDE;
    }
    const int  myCtr    = (bid * 4 + (tid >> 6)) * CTR_STRIDE;
    const bool waveLead = ((tid & 63) == 0);

    float Q = 0.0f, Ip = 0.0f;
    int cachedCons = -0x40000000;

    // -------- prologue: load batch 0 ---------------------------------------
    float latCur[BATCH], latNxt[BATCH];
    unsigned long long pendCur[BATCH], pendNxt[BATCH];
#pragma unroll
    for (int j = 0; j < BATCH; ++j)
        latCur[j] = lat[(size_t)j * NR_TOTAL + rr];
    if (hasProd && validT) {
#pragma unroll
        for (int j = 0; j < BATCH; ++j)
            pendCur[j] = ATOMIC_LD_RLX(ringUp + (size_t)j * size + e);
    }

    for (int bi = 0; bi < NBATCH; ++bi) {
        const int tb = bi * BATCH;

        // ---- prefetch NEXT batch (hidden under this batch's compute) ------
        if (bi + 1 < NBATCH) {
#pragma unroll
            for (int j = 0; j < BATCH; ++j)
                latNxt[j] = lat[(size_t)(tb + BATCH + j) * NR_TOTAL + rr];
            if (hasProd && validT) {
                const unsigned long long* upN =
                    ringUp + (size_t)((bi + 1) & sBm1) * upSlotSz + e;
#pragma unroll
                for (int j = 0; j < BATCH; ++j)
                    pendNxt[j] = ATOMIC_LD_RLX(upN + j * size);
            }
        }

        // ---- prefetch consumer progress (non-blocking) --------------------
        int pfCons = -0x40000000;
        const int need = (bi - slotsB + 1) * BATCH;
        if (hasCons && bi >= slotsB && cachedCons < need) {
            int v0 = ATOMIC_LD_RLX(&prog[c0i]);
            int v1 = (c1i == c0i) ? v0 : ATOMIC_LD_RLX(&prog[c1i]);
            pfCons = (v0 < v1) ? v0 : v1;
        }

        // ---- verify current-batch tags (steady state: all match) ----------
        if (hasProd && validT) {
            const unsigned long long* upC =
                ringUp + (size_t)(bi & sBm1) * upSlotSz + e;
#pragma unroll
            for (int j = 0; j < BATCH; ++j) {
                const unsigned tagWant = (unsigned)(tb + j + 1);
                unsigned long long v = pendCur[j];
                int spin = 0;
                while ((unsigned)(v >> 32) != tagWant) {
                    if (((++spin) & 63) == 0) __builtin_amdgcn_s_sleep(1);
                    v = ATOMIC_LD_RLX(upC + (size_t)j * size);
                }
                pendCur[j] = v;
            }
        }

        // ---- compute the 8 steps ------------------------------------------
        float qs[BATCH];
#pragma unroll
        for (int j = 0; j < BATCH; ++j) {
            float inflow = latCur[j];
            if (hasProd && validT)
                inflow += __uint_as_float((unsigned)pendCur[j]);

            float q = Q;
            const float ti  = inflow;
            const float t13 = ti * (1.0f/3.0f);
            const float t23 = ti * (2.0f/3.0f);
            const float dti = (2.0f * DT_SUB_F) * ti;
            {   // substep 0: io = Ip
                const float io = Ip;
                float Qref = fmaxf(fmaf(io + q, 1.0f/3.0f, t13), EPS_F);
                float lq   = FAST_LOG2(Qref);
                float K2   = sw_exp2(fmaf(eK, lq, cK2));
                float t    = sw_exp2(fmaf(et, lq, ct));
                float X    = fmaxf(0.5f - t, 0.0f);
                float KX2  = K2 * X;
                float A    = K2 - KX2;
                float rD   = FAST_RCP(A + DT_SUB_F);
                float num  = fmaf(A, q, fmaf(KX2, io - ti,
                                   DT_SUB_F * ((ti + io) - q)));
                q = fmaxf(num * rD, 0.0f);
            }
#pragma unroll
            for (int s = 1; s < 4; ++s) {   // substeps 1..3: io == inflow
                float Qref = fmaxf(fmaf(q, 1.0f/3.0f, t23), EPS_F);
                float lq   = FAST_LOG2(Qref);
                float K2   = sw_exp2(fmaf(eK, lq, cK2));
                float t    = sw_exp2(fmaf(et, lq, ct));
                float X    = fmaxf(0.5f - t, 0.0f);
                float A    = K2 - K2 * X;
                float rD   = FAST_RCP(A + DT_SUB_F);
                float num  = fmaf(A, q, fmaf(-DT_SUB_F, q, dti)); // +DT*(2ti-q)
                q = fmaxf(num * rD, 0.0f);
            }
            Q = q; Ip = inflow;

            if (hasCons) qs[j] = q + __shfl_xor(q, 1);
            else if (tid == 0) out[tb + j] = q;
        }

        // ---- back-pressure, then store the batch --------------------------
        if (hasCons) {
            if (bi >= slotsB && cachedCons < need) {
                if (pfCons >= need) {
                    cachedCons = pfCons;
                } else {
                    int spin = 0;
                    for (;;) {
                        int v0 = ATOMIC_LD_RLX(&prog[c0i]);
                        int v1 = (c1i == c0i) ? v0 : ATOMIC_LD_RLX(&prog[c1i]);
                        int m  = (v0 < v1) ? v0 : v1;
                        if (m >= need) { cachedCons = m; break; }
                        if (((++spin) & 63) == 0) __builtin_amdgcn_s_sleep(1);
                    }
                }
            }
            if (validT && ((tid & 1) == 0)) {
                unsigned long long* st = ringMy + (size_t)(bi & sBm1) * mySlotSz + (e >> 1);
#pragma unroll
                for (int j = 0; j < BATCH; ++j) {
                    unsigned long long v =
                        ((unsigned long long)(unsigned)(tb + j + 1) << 32) |
                        (unsigned long long)__float_as_uint(qs[j]);
                    ATOMIC_ST_RLX(st + (size_t)j * halfSize, v);
                }
            }
        }

        // ---- publish per-wave consumed progress ---------------------------
        if (waveLead) {
            int pubv = tb + BATCH;
            __asm__ volatile("" : "+v"(pubv) : "v"(Q));  // orders after ring reads
            ATOMIC_ST_RLX(&prog[myCtr], pubv);
        }

        // ---- swap prefetch buffers ----------------------------------------
#pragma unroll
        for (int j = 0; j < BATCH; ++j) {
            latCur[j]  = latNxt[j];
            pendCur[j] = pendNxt[j];
        }
    }
}

extern "C" void kernel_launch(void* const* d_in, const int* in_sizes, int n_in,
                              void* d_out, int out_size, void* d_ws, size_t ws_size,
                              hipStream_t stream) {
    const float* lat   = (const float*)d_in[0];
    const float* logn  = (const float*)d_in[1];
    const float* len   = (const float*)d_in[2];
    const float* slope = (const float*)d_in[3];
    const float* wc    = (const float*)d_in[4];
    const float* we    = (const float*)d_in[5];
    const float* dc    = (const float*)d_in[6];
    const float* de    = (const float*)d_in[7];
    float* out = (float*)d_out;

    int* prog = (int*)d_ws;
    unsigned long long* ring = (unsigned long long*)((char*)d_ws + RING_BYTE_OFF);

    int slotsB = 8;
    while (slotsB > 1) {
        size_t needB = (size_t)RING_BYTE_OFF + (size_t)8191 * 8 * 8 * slotsB;
        if (needB <= ws_size) break;
        slotsB >>= 1;
    }

    mc_route_pipe9<<<NBLOCKS, 256, 0, stream>>>(lat, logn, len, slope, wc, we, dc, de,
                                                out, prog, ring, slotsB);
}

// Round 10
// 895.795 us; speedup vs baseline: 1.4339x; 1.4339x over previous
//
#include <hip/hip_runtime.h>
#include <math.h>
#include <stdint.h>

// ---------------------------------------------------------------------------
// Muskingum-Cunge tree routing, spatially-pipelined persistent kernel, v10.
//
// Model after v3/v5/v8/v9: period = ~12cy/trans + ~5cy/VALU-inst + ~320cy/step
// fixed glue. v8 (more trans) and v9 (SW exp2, more VALU) both regressed ->
// v5's 16-hw-trans inner loop is the best known. v10 reverts to v5 math and
// attacks the glue:
//   (1) __shfl_xor -> DPP quad_perm pair-swap (2 VALU, no LDS, no lgkmcnt
//       wait; shfl lowers to ds_bpermute with ~100cy latency per step).
//   (2) BATCH 8->16: per-batch overhead halves per step.
//   (3) 2x-unrolled batch loop with ping-pong register banks: kills the
//       24-mov buffer swap per batch.
// Protocol unchanged: per-level persistent blocks, batched ring handoff,
// tagged 8-byte relaxed agent-scope atomics (sc0 sc1, MALL-coherent, no bulk
// cache maintenance), next-batch register prefetch, per-wave progress
// counters, no barriers/fences in the steady path.
// ---------------------------------------------------------------------------

#define N_LEVELS   14
#define T_STEPS    2048
#define NR_TOTAL   16383
#define DT_SUB_F   21600.0f
#define EPS_F      1e-6f
#define NBLOCKS    71
#define CTR_STRIDE 8             // ints per wave counter (32 B apart)
#define RING_BYTE_OFF 16384

__device__ __constant__ int kSize[N_LEVELS] = {8192,4096,2048,1024,512,256,128,64,32,16,8,4,2,1};
__device__ __constant__ int kEpb [N_LEVELS] = {256,256,256,256,256,256,128,64,32,16,8,4,2,1};
__device__ __constant__ int kBlkStart[N_LEVELS+1] = {0,32,48,56,60,62,63,64,65,66,67,68,69,70,71};
__device__ __constant__ int kOffL[N_LEVELS] = {0,8192,12288,14336,15360,15872,16128,16256,16320,16352,16368,16376,16380,16382};
// pair-sum entries before level l
__device__ __constant__ int kOffH[N_LEVELS-1] = {0,4096,6144,7168,7680,7936,8064,8128,8160,8176,8184,8188,8190};

#if __has_builtin(__builtin_amdgcn_exp2f)
#define FAST_EXP2(x) __builtin_amdgcn_exp2f(x)
#else
#define FAST_EXP2(x) exp2f(x)
#endif
#if __has_builtin(__builtin_amdgcn_logf)
#define FAST_LOG2(x) __builtin_amdgcn_logf(x)
#else
#define FAST_LOG2(x) log2f(x)
#endif
#if __has_builtin(__builtin_amdgcn_rcpf)
#define FAST_RCP(x) __builtin_amdgcn_rcpf(x)
#else
#define FAST_RCP(x) (1.0f/(x))
#endif

// pair sum of lanes (2k,2k+1) via DPP quad_perm [1,0,3,2]: pure VALU, no LDS.
__device__ __forceinline__ float pair_sum(float x) {
    int yi = __builtin_amdgcn_update_dpp(0, __float_as_int(x),
                                         0xB1 /*quad_perm 1,0,3,2*/,
                                         0xF, 0xF, true);
    return x + __int_as_float(yi);
}

#define ATOMIC_LD_RLX(p)   __hip_atomic_load((p), __ATOMIC_RELAXED, __HIP_MEMORY_SCOPE_AGENT)
#define ATOMIC_ST_RLX(p,v) __hip_atomic_store((p), (v), __ATOMIC_RELAXED, __HIP_MEMORY_SCOPE_AGENT)

template<int B>
__global__ __launch_bounds__(256)
void mc_route_pipe10(const float* __restrict__ lat,
                     const float* __restrict__ logn,
                     const float* __restrict__ len,
                     const float* __restrict__ slope,
                     const float* __restrict__ wcoef,
                     const float* __restrict__ wexp,
                     const float* __restrict__ dcoef,
                     const float* __restrict__ dexp,
                     float* __restrict__ out,
                     int* __restrict__ prog,
                     unsigned long long* __restrict__ ring,
                     int slotsB)
{
    const int bid = blockIdx.x;
    const int tid = threadIdx.x;
    const int NB  = T_STEPS / B;

    int lvl = 0;
#pragma unroll
    for (int l = 1; l < N_LEVELS; ++l)
        if (bid >= kBlkStart[l]) lvl = l;

    const int  bl     = bid - kBlkStart[lvl];
    const int  epb    = kEpb[lvl];
    const int  size   = kSize[lvl];
    const bool validT = (tid < epb);
    const int  e      = bl * epb + (validT ? tid : (epb - 1));
    const int  rr     = kOffL[lvl] + e;

    // -------- per-reach constants (chain-fused form, v5-verified) ----------
    const float dx      = len[rr];
    const float S       = slope[rr];
    const float sqrtS_n = sqrtf(S) * expf(-logn[rr]);        // sqrt(S)/n
    const float de23    = 0.66666667f * dexp[rr];
    const float l2dc    = log2f(dcoef[rr]);
    const float l2base  = log2f(0.6f / sqrtS_n) - 0.66666667f * l2dc;
    const float eK      = -de23;
    const float cK2     = log2f(2.0f * dx) + l2base;
    const float et      = 1.0f - de23 - wexp[rr];
    const float ct      = log2f(0.5f / (S * dx)) + l2base - log2f(wcoef[rr]);

    // -------- pipeline wiring ----------------------------------------------
    const bool hasProd = (lvl > 0);
    const bool hasCons = (lvl < N_LEVELS - 1);
    const int  SBB     = slotsB * B;
    const int  sBm1    = slotsB - 1;
    const unsigned long long* ringUp = hasProd ? ring + (size_t)kOffH[lvl-1] * SBB : ring;
    unsigned long long*       ringMy = hasCons ? ring + (size_t)kOffH[lvl]   * SBB : ring;
    const int halfSize = size >> 1;
    const int upSlotSz = size * B;
    const int mySlotSz = halfSize * B;

    int c0i = 0, c1i = 0;
    if (hasCons) {
        const int ceLo = (bl * epb) >> 1;
        const int ceHi = ((bl + 1) * epb - 1) >> 1;
        const int epbN = kEpb[lvl+1];
        const int cb   = kBlkStart[lvl+1] + ceLo / epbN;
        const int le0  = ceLo - (ceLo / epbN) * epbN;
        const int le1  = ceHi - (ceHi / epbN) * epbN;
        c0i = (cb * 4 + (le0 >> 6)) * CTR_STRIDE;
        c1i = (cb * 4 + (le1 >> 6)) * CTR_STRIDE;
    }
    const int  myCtr    = (bid * 4 + (tid >> 6)) * CTR_STRIDE;
    const bool waveLead = ((tid & 63) == 0);

    float Q = 0.0f, Ip = 0.0f;
    int cachedCons = -0x40000000;

    float latA[B], latB[B];
    unsigned long long pendA[B], pendB[B];

    // -------- prologue: load batch 0 into bank A ---------------------------
#pragma unroll
    for (int j = 0; j < B; ++j)
        latA[j] = lat[(size_t)j * NR_TOTAL + rr];
    if (hasProd && validT) {
#pragma unroll
        for (int j = 0; j < B; ++j)
            pendA[j] = ATOMIC_LD_RLX(ringUp + (size_t)j * size + e);
    }

    auto body = [&](int bi, float* latC, unsigned long long* pendC,
                    float* latN, unsigned long long* pendN) {
        const int tb = bi * B;

        // ---- prefetch NEXT batch into the other bank ----------------------
        if (bi + 1 < NB) {
#pragma unroll
            for (int j = 0; j < B; ++j)
                latN[j] = lat[(size_t)(tb + B + j) * NR_TOTAL + rr];
            if (hasProd && validT) {
                const unsigned long long* upN =
                    ringUp + (size_t)((bi + 1) & sBm1) * upSlotSz + e;
#pragma unroll
                for (int j = 0; j < B; ++j)
                    pendN[j] = ATOMIC_LD_RLX(upN + (size_t)j * size);
            }
        }

        // ---- prefetch consumer progress (non-blocking) --------------------
        int pfCons = -0x40000000;
        const int need = (bi - slotsB + 1) * B;
        if (hasCons && bi >= slotsB && cachedCons < need) {
            int v0 = ATOMIC_LD_RLX(&prog[c0i]);
            int v1 = (c1i == c0i) ? v0 : ATOMIC_LD_RLX(&prog[c1i]);
            pfCons = (v0 < v1) ? v0 : v1;
        }

        // ---- verify current-batch tags (steady state: all match) ----------
        if (hasProd && validT) {
            const unsigned long long* upC =
                ringUp + (size_t)(bi & sBm1) * upSlotSz + e;
#pragma unroll
            for (int j = 0; j < B; ++j) {
                const unsigned tagWant = (unsigned)(tb + j + 1);
                unsigned long long v = pendC[j];
                int spin = 0;
                while ((unsigned)(v >> 32) != tagWant) {
                    if (((++spin) & 63) == 0) __builtin_amdgcn_s_sleep(1);
                    v = ATOMIC_LD_RLX(upC + (size_t)j * size);
                }
                pendC[j] = v;
            }
        }

        // ---- compute the B steps ------------------------------------------
        float qs[B];
#pragma unroll
        for (int j = 0; j < B; ++j) {
            float inflow = latC[j];
            if (hasProd && validT)
                inflow += __uint_as_float((unsigned)pendC[j]);

            float q = Q;
            const float ti  = inflow;
            const float t13 = ti * (1.0f/3.0f);
            const float t23 = ti * (2.0f/3.0f);
            const float dti = (2.0f * DT_SUB_F) * ti;
            {   // substep 0: io = Ip
                const float io = Ip;
                float Qref = fmaxf(fmaf(io + q, 1.0f/3.0f, t13), EPS_F);
                float lq   = FAST_LOG2(Qref);
                float K2   = FAST_EXP2(fmaf(eK, lq, cK2));
                float t    = FAST_EXP2(fmaf(et, lq, ct));
                float X    = fmaxf(0.5f - t, 0.0f);
                float KX2  = K2 * X;
                float A    = K2 - KX2;
                float rD   = FAST_RCP(A + DT_SUB_F);
                float num  = fmaf(A, q, fmaf(KX2, io - ti,
                                   DT_SUB_F * ((ti + io) - q)));
                q = fmaxf(num * rD, 0.0f);
            }
#pragma unroll
            for (int s = 1; s < 4; ++s) {   // substeps 1..3: io == inflow
                float Qref = fmaxf(fmaf(q, 1.0f/3.0f, t23), EPS_F);
                float lq   = FAST_LOG2(Qref);
                float K2   = FAST_EXP2(fmaf(eK, lq, cK2));
                float t    = FAST_EXP2(fmaf(et, lq, ct));
                float X    = fmaxf(0.5f - t, 0.0f);
                float A    = K2 - K2 * X;
                float rD   = FAST_RCP(A + DT_SUB_F);
                float num  = fmaf(A, q, fmaf(-DT_SUB_F, q, dti)); // +DT*(2ti-q)
                q = fmaxf(num * rD, 0.0f);
            }
            Q = q; Ip = inflow;

            if (hasCons) qs[j] = pair_sum(q);        // DPP, no LDS
            else if (tid == 0) out[tb + j] = q;
        }

        // ---- back-pressure, then store the batch --------------------------
        if (hasCons) {
            if (bi >= slotsB && cachedCons < need) {
                if (pfCons >= need) {
                    cachedCons = pfCons;
                } else {
                    int spin = 0;
                    for (;;) {
                        int v0 = ATOMIC_LD_RLX(&prog[c0i]);
                        int v1 = (c1i == c0i) ? v0 : ATOMIC_LD_RLX(&prog[c1i]);
                        int m  = (v0 < v1) ? v0 : v1;
                        if (m >= need) { cachedCons = m; break; }
                        if (((++spin) & 63) == 0) __builtin_amdgcn_s_sleep(1);
                    }
                }
            }
            if (validT && ((tid & 1) == 0)) {
                unsigned long long* st = ringMy + (size_t)(bi & sBm1) * mySlotSz + (e >> 1);
#pragma unroll
                for (int j = 0; j < B; ++j) {
                    unsigned long long v =
                        ((unsigned long long)(unsigned)(tb + j + 1) << 32) |
                        (unsigned long long)__float_as_uint(qs[j]);
                    ATOMIC_ST_RLX(st + (size_t)j * halfSize, v);
                }
            }
        }

        // ---- publish per-wave consumed progress ---------------------------
        if (waveLead) {
            int pubv = tb + B;
            __asm__ volatile("" : "+v"(pubv) : "v"(Q));  // orders after ring reads
            ATOMIC_ST_RLX(&prog[myCtr], pubv);
        }
    };

    // 2x-unrolled batch loop, ping-pong banks (no swap movs)
    for (int bi = 0; bi < NB; bi += 2) {
        body(bi,     latA, pendA, latB, pendB);
        body(bi + 1, latB, pendB, latA, pendA);
    }
}

extern "C" void kernel_launch(void* const* d_in, const int* in_sizes, int n_in,
                              void* d_out, int out_size, void* d_ws, size_t ws_size,
                              hipStream_t stream) {
    const float* lat   = (const float*)d_in[0];
    const float* logn  = (const float*)d_in[1];
    const float* len   = (const float*)d_in[2];
    const float* slope = (const float*)d_in[3];
    const float* wc    = (const float*)d_in[4];
    const float* we    = (const float*)d_in[5];
    const float* dc    = (const float*)d_in[6];
    const float* de    = (const float*)d_in[7];
    float* out = (float*)d_out;

    int* prog = (int*)d_ws;
    unsigned long long* ring = (unsigned long long*)((char*)d_ws + RING_BYTE_OFF);

    auto needBytes = [](int Bv, int Sv) {
        return (size_t)RING_BYTE_OFF + (size_t)8191 * 8 * Bv * Sv;
    };

    if (needBytes(16, 8) <= ws_size) {
        mc_route_pipe10<16><<<NBLOCKS, 256, 0, stream>>>(lat, logn, len, slope, wc, we, dc, de,
                                                         out, prog, ring, 8);
    } else if (needBytes(16, 4) <= ws_size) {
        mc_route_pipe10<16><<<NBLOCKS, 256, 0, stream>>>(lat, logn, len, slope, wc, we, dc, de,
                                                         out, prog, ring, 4);
    } else if (needBytes(16, 2) <= ws_size) {
        mc_route_pipe10<16><<<NBLOCKS, 256, 0, stream>>>(lat, logn, len, slope, wc, we, dc, de,
                                                         out, prog, ring, 2);
    } else if (needBytes(8, 4) <= ws_size) {
        mc_route_pipe10<8><<<NBLOCKS, 256, 0, stream>>>(lat, logn, len, slope, wc, we, dc, de,
                                                        out, prog, ring, 4);
    } else {
        mc_route_pipe10<8><<<NBLOCKS, 256, 0, stream>>>(lat, logn, len, slope, wc, we, dc, de,
                                                        out, prog, ring, 2);
    }
}